// Round 1
// baseline (159.125 us; speedup 1.0000x reference)
//
#include <hip/hip_runtime.h>
#include <hip/hip_bf16.h>

// Triangle attention (start) — N=256, C=128, H=4, D=32, f16 MFMA pipeline.
// Stage 1: prep weights (transpose -> f16, so every MFMA fragment is one 16B load)
// Stage 2: LayerNorm -> z (f16)
// Stage 3: fused projections q,k,v,gate (+ pair bias) via mfma_f32_16x16x32_f16
// Stage 4: per-(h,i) attention: QK^T + bias -> softmax (in-reg, shfl) -> PV -> *gate
// Stage 5: out = O @ Wo + bo (f32)

typedef _Float16 half8 __attribute__((ext_vector_type(8)));
typedef float floatx4 __attribute__((ext_vector_type(4)));

#define NN 256
#define CC 128
#define HH 4
#define DD 32
#define NR (NN*NN)          // 65536 rows
#define LN_EPS 1e-5f
#define PSLD 264            // LDS row pad: 264 f16 = 528B -> bank step 4, ~2-way (free)

// ---------------- Stage 1: weight prep ----------------
__global__ __launch_bounds__(256) void prep_weights(
    const float* __restrict__ Wq, const float* __restrict__ Wk,
    const float* __restrict__ Wv, const float* __restrict__ Wg,
    const float* __restrict__ Wo, const float* __restrict__ Wb,
    _Float16* __restrict__ WqT, _Float16* __restrict__ WkT,
    _Float16* __restrict__ WvT, _Float16* __restrict__ WgT,
    _Float16* __restrict__ WoT, _Float16* __restrict__ WbT)
{
    int id = blockIdx.x * 256 + threadIdx.x;
    if (id < 5 * 16384) {
        int m = id / 16384, e = id % 16384;
        int n = e >> 7, c = e & 127;
        const float* src = (m==0)?Wq:(m==1)?Wk:(m==2)?Wv:(m==3)?Wg:Wo;
        _Float16* dst    = (m==0)?WqT:(m==1)?WkT:(m==2)?WvT:(m==3)?WgT:WoT;
        dst[n*128 + c] = (_Float16)src[c*128 + n];
    } else {
        int e = id - 5*16384;   // WbT padded to [16][128]
        if (e < 16*128) {
            int n = e >> 7, c = e & 127;
            WbT[n*128 + c] = (n < HH) ? (_Float16)Wb[c*HH + n] : (_Float16)0.f;
        }
    }
}

// ---------------- Stage 2: LayerNorm ----------------
__global__ __launch_bounds__(256) void ln_kernel(
    const float* __restrict__ x, const float* __restrict__ scale,
    const float* __restrict__ bias, _Float16* __restrict__ zh)
{
    int wave = threadIdx.x >> 6;
    int lane = threadIdx.x & 63;
    int row  = blockIdx.x * 4 + wave;
    float2 v = *(const float2*)&x[(size_t)row*CC + lane*2];
    float s  = v.x + v.y;
    float ss = v.x*v.x + v.y*v.y;
    #pragma unroll
    for (int off = 1; off < 64; off <<= 1) {
        s  += __shfl_xor(s,  off);
        ss += __shfl_xor(ss, off);
    }
    float mu   = s * (1.f/128.f);
    float var  = ss * (1.f/128.f) - mu*mu;
    float rstd = rsqrtf(var + LN_EPS);
    float z0 = (v.x - mu) * rstd * scale[lane*2]   + bias[lane*2];
    float z1 = (v.y - mu) * rstd * scale[lane*2+1] + bias[lane*2+1];
    union { _Float16 h[2]; unsigned u; } pk;
    pk.h[0] = (_Float16)z0; pk.h[1] = (_Float16)z1;
    *(unsigned*)&zh[(size_t)row*CC + lane*2] = pk.u;
}

// ---------------- Stage 3: fused projections ----------------
__global__ __launch_bounds__(256) void proj_kernel(
    const _Float16* __restrict__ zh,
    const _Float16* __restrict__ WqT, const _Float16* __restrict__ WkT,
    const _Float16* __restrict__ WvT, const _Float16* __restrict__ WgT,
    const _Float16* __restrict__ WbT, const float* __restrict__ bg,
    _Float16* __restrict__ qh, _Float16* __restrict__ kh,
    _Float16* __restrict__ vh, _Float16* __restrict__ gh,
    float* __restrict__ biasF)
{
    int wave = threadIdx.x >> 6, lane = threadIdx.x & 63;
    int mtile = blockIdx.x * 4 + wave;          // 16-row tile of 65536 rows
    int lr = lane & 15, lg = lane >> 4;

    // A fragments (16 rows x K=128), loaded once, reused for all 4 projections.
    half8 afrag[4];
    const _Float16* arow = &zh[((size_t)mtile*16 + lr)*CC + lg*8];
    #pragma unroll
    for (int ks = 0; ks < 4; ++ks) afrag[ks] = *(const half8*)&arow[ks*32];

    const _Float16* Ws[4]  = {WqT, WkT, WvT, WgT};
    _Float16*       outs[4] = {qh, kh, vh, gh};

    for (int p = 0; p < 4; ++p) {
        const _Float16* WT = Ws[p];
        floatx4 acc[8];
        #pragma unroll
        for (int nt = 0; nt < 8; ++nt) acc[nt] = (floatx4){0.f,0.f,0.f,0.f};
        #pragma unroll
        for (int nt = 0; nt < 8; ++nt) {
            #pragma unroll
            for (int ks = 0; ks < 4; ++ks) {
                half8 b = *(const half8*)&WT[(nt*16 + lr)*128 + ks*32 + lg*8];
                acc[nt] = __builtin_amdgcn_mfma_f32_16x16x32_f16(afrag[ks], b, acc[nt], 0, 0, 0);
            }
        }
        #pragma unroll
        for (int nt = 0; nt < 8; ++nt) {
            #pragma unroll
            for (int r = 0; r < 4; ++r) {
                int row = mtile*16 + lg*4 + r;
                int col = nt*16 + lr;
                float val = acc[nt][r];
                if (p == 0) val *= 0.17677669529663687f;            // 1/sqrt(32)
                if (p == 3) val = 1.f / (1.f + __expf(-(val + bg[col])));  // gate
                outs[p][(size_t)row*CC + col] = (_Float16)val;
            }
        }
    }

    // pair bias: z @ Wb  (WbT padded to 16 cols, cols >=4 are zero)
    floatx4 acc2 = (floatx4){0.f,0.f,0.f,0.f};
    #pragma unroll
    for (int ks = 0; ks < 4; ++ks) {
        half8 b = *(const half8*)&WbT[lr*128 + ks*32 + lg*8];
        acc2 = __builtin_amdgcn_mfma_f32_16x16x32_f16(afrag[ks], b, acc2, 0, 0, 0);
    }
    if (lr < HH) {
        #pragma unroll
        for (int r = 0; r < 4; ++r) {
            int rr = mtile*16 + lg*4 + r;         // rr = a*256 + b
            biasF[(size_t)lr*NR + rr] = acc2[r];  // biasF[h][a][b]
        }
    }
}

// ---------------- Stage 4: attention per (h, i) ----------------
__global__ __launch_bounds__(256) void attn_kernel(
    const _Float16* __restrict__ qh, const _Float16* __restrict__ kh,
    const _Float16* __restrict__ vh, const _Float16* __restrict__ gh,
    const float* __restrict__ biasF, _Float16* __restrict__ oh)
{
    __shared__ _Float16 Vt[DD][PSLD];        // V transposed: Vt[d][k]
    __shared__ _Float16 Ps[4][16][PSLD];     // per-wave P tile

    int ib = blockIdx.x;       // i (row index of pair)
    int h  = blockIdx.y;       // head
    int tid = threadIdx.x;
    int wave = tid >> 6, lane = tid & 63;
    int lr = lane & 15, lg = lane >> 4;
    size_t rbase = (size_t)ib * NN;

    // stage V transposed into LDS (coalesced reads: 32 consecutive d per 32 lanes)
    {
        int d = tid & 31;
        for (int kk = tid >> 5; kk < NN; kk += 8)
            Vt[d][kk] = vh[(rbase + kk)*CC + h*DD + d];
    }
    __syncthreads();

    for (int jt = wave; jt < 16; jt += 4) {
        // ---- S = Q K^T (K-dim = D = 32: single MFMA k-step) ----
        half8 aq = *(const half8*)&qh[(rbase + jt*16 + lr)*CC + h*DD + lg*8];
        floatx4 zero = (floatx4){0.f,0.f,0.f,0.f};
        floatx4 sacc[16];
        #pragma unroll
        for (int nt = 0; nt < 16; ++nt) {
            half8 bk = *(const half8*)&kh[(rbase + nt*16 + lr)*CC + h*DD + lg*8];
            sacc[nt] = __builtin_amdgcn_mfma_f32_16x16x32_f16(aq, bk, zero, 0, 0, 0);
        }

        // ---- + bias, row max ----
        float m[4];
        #pragma unroll
        for (int r = 0; r < 4; ++r) m[r] = -1e30f;
        #pragma unroll
        for (int nt = 0; nt < 16; ++nt) {
            #pragma unroll
            for (int r = 0; r < 4; ++r) {
                int j = jt*16 + lg*4 + r;
                sacc[nt][r] += biasF[(size_t)h*NR + j*NN + nt*16 + lr];
                m[r] = fmaxf(m[r], sacc[nt][r]);
            }
        }
        #pragma unroll
        for (int r = 0; r < 4; ++r) {
            #pragma unroll
            for (int off = 1; off < 16; off <<= 1)
                m[r] = fmaxf(m[r], __shfl_xor(m[r], off));
        }

        // ---- exp + row sum ----
        float ssum[4] = {0.f, 0.f, 0.f, 0.f};
        #pragma unroll
        for (int nt = 0; nt < 16; ++nt) {
            #pragma unroll
            for (int r = 0; r < 4; ++r) {
                float p = __expf(sacc[nt][r] - m[r]);
                sacc[nt][r] = p;
                ssum[r] += p;
            }
        }
        #pragma unroll
        for (int r = 0; r < 4; ++r) {
            #pragma unroll
            for (int off = 1; off < 16; off <<= 1)
                ssum[r] += __shfl_xor(ssum[r], off);
            ssum[r] = 1.f / ssum[r];
        }

        // ---- normalized P -> LDS (transpose to A-fragment layout) ----
        #pragma unroll
        for (int nt = 0; nt < 16; ++nt) {
            #pragma unroll
            for (int r = 0; r < 4; ++r)
                Ps[wave][lg*4 + r][nt*16 + lr] = (_Float16)(sacc[nt][r] * ssum[r]);
        }
        // same-wave LDS RAW dependence: compiler inserts lgkmcnt wait.

        // ---- O = P V ----
        floatx4 oacc[2];
        oacc[0] = zero; oacc[1] = zero;
        #pragma unroll
        for (int ks = 0; ks < 8; ++ks) {
            half8 ap = *(const half8*)&Ps[wave][lr][ks*32 + lg*8];
            #pragma unroll
            for (int nt2 = 0; nt2 < 2; ++nt2) {
                half8 bv = *(const half8*)&Vt[nt2*16 + lr][ks*32 + lg*8];
                oacc[nt2] = __builtin_amdgcn_mfma_f32_16x16x32_f16(ap, bv, oacc[nt2], 0, 0, 0);
            }
        }

        // ---- * gate, store f16 ----
        #pragma unroll
        for (int nt2 = 0; nt2 < 2; ++nt2) {
            #pragma unroll
            for (int r = 0; r < 4; ++r) {
                int j = jt*16 + lg*4 + r;
                int d = nt2*16 + lr;
                float g = (float)gh[(rbase + j)*CC + h*DD + d];
                oh[(rbase + j)*CC + h*DD + d] = (_Float16)(oacc[nt2][r] * g);
            }
        }
    }
}

// ---------------- Stage 5: output projection ----------------
__global__ __launch_bounds__(256) void out_kernel(
    const _Float16* __restrict__ oh, const _Float16* __restrict__ WoT,
    const float* __restrict__ bo, float* __restrict__ out)
{
    int wave = threadIdx.x >> 6, lane = threadIdx.x & 63;
    int mtile = blockIdx.x * 4 + wave;
    int lr = lane & 15, lg = lane >> 4;

    half8 afrag[4];
    const _Float16* arow = &oh[((size_t)mtile*16 + lr)*CC + lg*8];
    #pragma unroll
    for (int ks = 0; ks < 4; ++ks) afrag[ks] = *(const half8*)&arow[ks*32];

    floatx4 acc[8];
    #pragma unroll
    for (int nt = 0; nt < 8; ++nt) acc[nt] = (floatx4){0.f,0.f,0.f,0.f};
    #pragma unroll
    for (int nt = 0; nt < 8; ++nt) {
        #pragma unroll
        for (int ks = 0; ks < 4; ++ks) {
            half8 b = *(const half8*)&WoT[(nt*16 + lr)*128 + ks*32 + lg*8];
            acc[nt] = __builtin_amdgcn_mfma_f32_16x16x32_f16(afrag[ks], b, acc[nt], 0, 0, 0);
        }
    }
    #pragma unroll
    for (int nt = 0; nt < 8; ++nt) {
        #pragma unroll
        for (int r = 0; r < 4; ++r) {
            int row = mtile*16 + lg*4 + r;
            int col = nt*16 + lr;
            out[(size_t)row*CC + col] = acc[nt][r] + bo[col];
        }
    }
}

// ---------------- launch ----------------
extern "C" void kernel_launch(void* const* d_in, const int* in_sizes, int n_in,
                              void* d_out, int out_size, void* d_ws, size_t ws_size,
                              hipStream_t stream)
{
    const float* pair     = (const float*)d_in[0];
    const float* ln_scale = (const float*)d_in[1];
    const float* ln_bias  = (const float*)d_in[2];
    const float* Wq       = (const float*)d_in[3];
    const float* Wk       = (const float*)d_in[4];
    const float* Wv       = (const float*)d_in[5];
    const float* Wb       = (const float*)d_in[6];
    const float* Wg       = (const float*)d_in[7];
    const float* bg       = (const float*)d_in[8];
    const float* Wo       = (const float*)d_in[9];
    const float* bo       = (const float*)d_in[10];
    float* out = (float*)d_out;

    char* ws = (char*)d_ws;
    const size_t MAT = (size_t)NR * CC * sizeof(_Float16);   // 16.78 MB
    _Float16* zh = (_Float16*)ws; ws += MAT;   // z, later reused as attention output O
    _Float16* qh = (_Float16*)ws; ws += MAT;
    _Float16* kh = (_Float16*)ws; ws += MAT;
    _Float16* vh = (_Float16*)ws; ws += MAT;
    _Float16* gh = (_Float16*)ws; ws += MAT;
    float* biasF = (float*)ws;    ws += (size_t)HH * NR * sizeof(float);  // 1 MB
    _Float16* WqT = (_Float16*)ws; ws += 128*128*sizeof(_Float16);
    _Float16* WkT = (_Float16*)ws; ws += 128*128*sizeof(_Float16);
    _Float16* WvT = (_Float16*)ws; ws += 128*128*sizeof(_Float16);
    _Float16* WgT = (_Float16*)ws; ws += 128*128*sizeof(_Float16);
    _Float16* WoT = (_Float16*)ws; ws += 128*128*sizeof(_Float16);
    _Float16* WbT = (_Float16*)ws; ws += 16*128*sizeof(_Float16);
    _Float16* oh = zh;   // proj_kernel is done with zh before attn writes it

    prep_weights<<<(5*16384 + 16*128 + 255)/256, 256, 0, stream>>>(
        Wq, Wk, Wv, Wg, Wo, Wb, WqT, WkT, WvT, WgT, WoT, WbT);

    ln_kernel<<<NR/4, 256, 0, stream>>>(pair, ln_scale, ln_bias, zh);

    proj_kernel<<<NR/16/4, 256, 0, stream>>>(
        zh, WqT, WkT, WvT, WgT, WbT, bg, qh, kh, vh, gh, biasF);

    attn_kernel<<<dim3(NN, HH), 256, 0, stream>>>(qh, kh, vh, gh, biasF, oh);

    out_kernel<<<NR/16/4, 256, 0, stream>>>(oh, WoT, bo, out);
}